// Round 4
// baseline (138.386 us; speedup 1.0000x reference)
//
#include <hip/hip_runtime.h>
#include <math.h>

#define T_LEN      24000
#define TS         1792          // samples per slice
#define NSLICE     14            // 14 * 1792 = 25088 >= 24000 (last slice: 704 valid)
#define W_LEN      81
#define HALF_W     40
#define NK         21
#define MAXORD     10
#define NIMG_TOTAL 1561          // |{k in [-10,10]^3 : |kx|+|ky|+|kz| <= 10}|
#define FS_F       48000.0f
#define C_F        343.0f
#define FS_OVER_C  (48000.0f / 343.0f)
#define PI_F       3.14159265358979323846f
#define FOUR_PI_F  12.566370614359172f
#define NEG_SLOPE  0.01f
#define NTHREADS   256

// ---- compile-time table of valid image triples ----
// entry: (order << 15) | (kxi << 10) | (kyi << 5) | kzi
struct Table { unsigned int e[NIMG_TOTAL]; };

constexpr Table make_table() {
    Table t{};
    int n = 0;
    for (int kx = 0; kx < NK; ++kx)
        for (int ky = 0; ky < NK; ++ky)
            for (int kz = 0; kz < NK; ++kz) {
                int ax = kx >= MAXORD ? kx - MAXORD : MAXORD - kx;
                int ay = ky >= MAXORD ? ky - MAXORD : MAXORD - ky;
                int az = kz >= MAXORD ? kz - MAXORD : MAXORD - kz;
                int order = ax + ay + az;
                if (order <= MAXORD)
                    t.e[n++] = (unsigned)((order << 15) | (kx << 10) | (ky << 5) | kz);
            }
    return t;
}
__constant__ Table g_tbl = make_table();

__global__ __launch_bounds__(NTHREADS)
void rir_wscatter_kernel(const float* __restrict__ g_in,
                         const float* __restrict__ W1, const float* __restrict__ b1,
                         const float* __restrict__ W2, const float* __restrict__ b2,
                         const float* __restrict__ W3, const float* __restrict__ b3,
                         float* __restrict__ out_rir, float* __restrict__ out_origin)
{
    __shared__ __align__(16) float rir[TS];          // 7168 B
    __shared__ float dsq[3 * NK];                    // (img - mic)^2 per axis
    __shared__ float bp[MAXORD + 1];                 // 0.9^o / (4*pi)
    __shared__ float h1[30], h2[20], zb[9], sm_in[22], rms[9];

    const int tid  = threadIdx.x;
    const int lane = tid & 63;
    const int s    = blockIdx.x;         // time slice
    const int b    = blockIdx.y;         // batch row
    const int lo   = s * TS;
    const int nout = min(TS, T_LEN - lo);   // 1792, or 704 for last slice

    // ---- zero the slice accumulator ----
    #pragma unroll
    for (int i = tid; i < TS; i += NTHREADS) rir[i] = 0.0f;

    // ---- per-lane tap constants (registers, no LDS in tap body) ----
    // round 1: tap j = lane; round 2: tap j = lane + 64 (lanes 0..16)
    const float nf1 = (float)(lane - HALF_W);
    const float hw1 = 0.5f * (1.0f - __cosf(2.0f * PI_F * (float)lane / 80.0f));
    const float hw2 = 0.5f * (1.0f - __cosf(2.0f * PI_F * (float)(lane + 64) / 80.0f));
    const float sg  = (lane & 1) ? 1.0f : -1.0f;   // sin(pi(n-frac)) = -(-1)^n sin(pi frac), parity(n)=parity(j)

    // ---- beta powers (wave 1 lanes, parallel with wave-0 MLP) ----
    if (tid >= 64 && tid < 64 + MAXORD + 1)
        bp[tid - 64] = powf(0.9f, (float)(tid - 64)) * (1.0f / FOUR_PI_F);

    // ---- wave 0: input row, MLP, geometry (in-wave LDS ordering, no barriers) ----
    if (tid < 64) {
        if (tid < 22) sm_in[tid] = g_in[b * 22 + tid];
        if (tid < 30) {
            float a = b1[tid];
            const float* w = W1 + tid * 22;
            #pragma unroll
            for (int i = 0; i < 22; ++i) a += sm_in[i] * w[i];
            h1[tid] = (a >= 0.0f) ? a : NEG_SLOPE * a;
        }
        if (tid < 20) {
            float a = b2[tid];
            const float* w = W2 + tid * 30;
            #pragma unroll
            for (int i = 0; i < 30; ++i) a += h1[i] * w[i];
            h2[tid] = (a >= 0.0f) ? a : NEG_SLOPE * a;
        }
        if (tid < 9) {
            float a = b3[tid];
            const float* w = W3 + tid * 20;
            #pragma unroll
            for (int i = 0; i < 20; ++i) a += h2[i] * w[i];
            zb[tid] = 1.0f / (1.0f + expf(-a));
        }
        if (tid < 3) {
            float room = zb[tid] * 20.0f;
            rms[tid]     = room;
            rms[3 + tid] = zb[3 + tid] * room;   // mic
            rms[6 + tid] = zb[6 + tid] * room;   // src
        }
        if (tid == 0 && s == 0) {
            float dx = rms[3] - rms[6], dy = rms[4] - rms[7], dz = rms[5] - rms[8];
            out_origin[b] = 40.0f + FS_F * sqrtf(dx * dx + dy * dy + dz * dz) / C_F;
        }
        if (tid < 3 * NK) {
            int a  = tid / NK;
            int kk = (tid - a * NK) - MAXORD;
            float L = rms[a], src = rms[6 + a];
            float img = ((kk & 1) == 0) ? (float)kk * L + src : (float)(kk + 1) * L - src;
            float diff = img - rms[3 + a];
            dsq[tid] = diff * diff;
        }
    }
    __syncthreads();

    // ---- wave-cooperative scatter ----
    const float lof = (float)(lo - HALF_W - 1);
    const float hif = (float)(min(lo + TS - 1, T_LEN - 1) + HALF_W + 1);

    for (int i0 = tid; (i0 - lane) < NIMG_TOTAL; i0 += NTHREADS) {
        const bool live = (i0 < NIMG_TOTAL);
        unsigned e = g_tbl.e[live ? i0 : 0];
        int kzi = e & 31, kyi = (e >> 5) & 31, kxi = (e >> 10) & 31, order = (int)(e >> 15);
        float d     = sqrtf(dsq[kxi] + dsq[NK + kyi] + dsq[2 * NK + kzi]);
        float delay = 40.0f + d * FS_OVER_C;
        float t0f   = floorf(delay);
        float ampv  = bp[order] * __builtin_amdgcn_rcpf(fmaxf(d, 0.001f));
        bool hit = live && (t0f >= lof) && (t0f <= hif);

        unsigned long long mask = __ballot(hit);
        while (mask) {
            int l = __builtin_ctzll(mask);
            mask &= mask - 1;
            // broadcast the hit image's parameters to the whole wave
            float amp    = __shfl(ampv, l);
            float delayu = __shfl(delay, l);
            float t0u  = floorf(delayu);
            float frac = delayu - t0u;
            float sp   = __sinf(PI_F * frac) * sg;       // per-lane signed sin
            int t0rel  = (int)t0u - lo;

            // round 1: taps j = 0..63
            int   idx1 = t0rel - HALF_W + lane;
            float x1   = nf1 - frac;                     // t - delay
            float sv1  = (x1 == 0.0f) ? 1.0f : sp * __builtin_amdgcn_rcpf(PI_F * x1);
            if ((unsigned)idx1 < (unsigned)nout)
                atomicAdd(&rir[idx1], amp * sv1 * hw1);

            // round 2: taps j = 64..80 (lanes 0..16)
            int   idx2 = idx1 + 64;
            float x2   = x1 + 64.0f;
            float sv2  = sp * __builtin_amdgcn_rcpf(PI_F * x2);   // x2 >= 23, never 0
            if (lane < 17 && (unsigned)idx2 < (unsigned)nout)
                atomicAdd(&rir[idx2], amp * sv2 * hw2);
        }
    }
    __syncthreads();

    // ---- coalesced writeback of this slice ----
    float4* out4 = (float4*)(out_rir + (size_t)b * T_LEN + lo);
    float4* rir4 = (float4*)rir;
    for (int i = tid; i < nout / 4; i += NTHREADS) out4[i] = rir4[i];
}

extern "C" void kernel_launch(void* const* d_in, const int* in_sizes, int n_in,
                              void* d_out, int out_size, void* d_ws, size_t ws_size,
                              hipStream_t stream) {
    const float* g_in = (const float*)d_in[0];
    const float* W1   = (const float*)d_in[1];
    const float* b1   = (const float*)d_in[2];
    const float* W2   = (const float*)d_in[3];
    const float* b2   = (const float*)d_in[4];
    const float* W3   = (const float*)d_in[5];
    const float* b3   = (const float*)d_in[6];

    const int B = in_sizes[0] / 22;

    float* out_rir    = (float*)d_out;
    float* out_origin = out_rir + (size_t)B * T_LEN;

    dim3 grid(NSLICE, B);
    rir_wscatter_kernel<<<grid, NTHREADS, 0, stream>>>(
        g_in, W1, b1, W2, b2, W3, b3, out_rir, out_origin);
}